// Round 5
// baseline (279.474 us; speedup 1.0000x reference)
//
#include <hip/hip_runtime.h>
#include <stdint.h>

typedef unsigned short u16;
typedef float v4f __attribute__((ext_vector_type(4)));
typedef short v8s __attribute__((ext_vector_type(8)));

#define B_   8192
#define IN_  1024
#define OUT_ 1024
#define D_   8

#define BM 256
#define BN 128
#define BK 64             // K-tile; 2 phases of 16 MFMA each per tile

__device__ __forceinline__ u16 f2bf(float f) {
  uint32_t u = __float_as_uint(f);
  u += 0x7fffu + ((u >> 16) & 1u);   // RTNE (inputs finite)
  return (u16)(u >> 16);
}

__device__ __forceinline__ uint32_t cvtpk(float lo, float hi) {
  uint32_t r;
  asm("v_cvt_pk_bf16_f32 %0, %1, %2" : "=v"(r) : "v"(lo), "v"(hi));
  return r;
}

// ---- prep: weights f32 -> bf16 (32 MB read + 16 MB write) ------------------
__global__ __launch_bounds__(256) void convert_w(
    const float* __restrict__ weights, u16* __restrict__ wtBf) {
  const int i4 = blockIdx.x * 256 + threadIdx.x;
  float4 v = ((const float4*)weights)[i4];
  ushort4 o;
  o.x = f2bf(v.x); o.y = f2bf(v.y); o.z = f2bf(v.z); o.w = f2bf(v.w);
  ((ushort4*)wtBf)[i4] = o;
}

__device__ __forceinline__ void gload_lds16(const u16* g, u16* l) {
  typedef __attribute__((address_space(1))) void gvoid;
  typedef __attribute__((address_space(3))) void lvoid;
  __builtin_amdgcn_global_load_lds((gvoid*)g, (lvoid*)l, 16, 0, 0);
}

// ---- 8-phase-style fused GEMM ----------------------------------------------
// R4 lesson (= guide m230/m228d): counted-vmcnt/setprio are NULL on the
// 2-barrier-per-K-tile structure; the phase-split schedule is the gate.
// m201 template adapted: BM=256 x BN=128, 512 thr (8 waves, 4M x 2N,
// per-wave 64x64 -> fragment layout identical to proven kernel), 1 block/CU
// (256 blocks). Per K-tile: 2 phases, each
//   {8 ds_read_b128 | stage slice | barrier | lgkmcnt(0) | 16 MFMA | barrier}
// A' (w-scaled bf16 input) staged from regs (f32 loaded once per it,
// rescaled per dd), double-buffered. B via global_load_lds, 4-deep buffer
// (period 4 == static under dd-unroll), issued 2 K-tiles ahead; counted
// vmcnt once per K-tile (2 steady / 10 at dd6 / 0 final only).
// LDS = 2*32KB (A) + 4*16KB (B) = 128 KB.
__global__ __launch_bounds__(512, 2) void gemm_8p(
    const float* __restrict__ Ain,    // [B_][IN_] f32 input (unscaled)
    const u16* __restrict__ Wt,       // [D_][OUT_][IN_] bf16
    const float* __restrict__ w,      // [B_][D_]
    const float* __restrict__ biases, // [D_][OUT_]
    float* __restrict__ out) {        // [B_][OUT_]
  __shared__ __align__(16) u16 As[2][BM * BK];   // 64 KB
  __shared__ __align__(16) u16 Bs[4][BN * BK];   // 64 KB

  const int id   = blockIdx.x;                // 256 blocks (1/CU)
  const int bx   = id & 7;                    // 8 N-tiles
  const int by   = id >> 3;                   // 32 M-tiles

  const int tid  = threadIdx.x;
  const int wid  = tid >> 6;                  // 0..7
  const int lane = tid & 63;
  const int wr   = wid >> 1, wc = wid & 1;    // 4M x 2N wave grid
  const int quad = lane >> 4, l16 = lane & 15;
  const int m0   = by * BM;
  const int n0   = bx * BN;

  // staging geometry (proven XOR swizzle, j-invariant):
  // A: 2048 chunks; c = wid*256 + j*64 + lane (j=0..3); row = c>>3
  // B: 1024 chunks; c = wid*128 + j*64 + lane (j=0..1)
  // LDS chunk (lane&7) of row holds global chunk swz = (lane&7)^((lane>>3)&7)
  const int swz   = (lane & 7) ^ ((lane >> 3) & 7);
  const int rowSA = wid * 32 + (lane >> 3);   // + j*8 -> 0..255
  const int rowSB = wid * 16 + (lane >> 3);   // + j*8 -> 0..127
  const float* aBase[4];
  const u16*   bBase[2];
  int aOffL[4], bOffL[2];
#pragma unroll
  for (int j = 0; j < 4; ++j) {
    aBase[j] = Ain + (size_t)(m0 + rowSA + j * 8) * IN_ + swz * 8;
    aOffL[j] = (wid * 256 + j * 64 + lane) * 8;
  }
#pragma unroll
  for (int j = 0; j < 2; ++j) {
    bBase[j] = Wt + (size_t)(n0 + rowSB + j * 8) * IN_ + swz * 8;
    bOffL[j] = (wid * 128 + j * 64 + lane) * 8;
  }

  // per-staging-row w[0..7] preloaded (static-index select under unroll)
  float4 wA[4], wB[4];
#pragma unroll
  for (int j = 0; j < 4; ++j) {
    const float* wp = w + (size_t)(m0 + rowSA + j * 8) * D_;
    wA[j] = ((const float4*)wp)[0];
    wB[j] = ((const float4*)wp)[1];
  }

  // fragment LDS offsets (u16 index), de-swizzled; identical to proven kernel
  const int aRow = wr * 64 + l16;             // 0..255
  const int bRow = wc * 64 + l16;             // 0..127
  const int e    = l16 & 7;
  int aC[2];
#pragma unroll
  for (int h = 0; h < 2; ++h) aC[h] = ((quad + 4 * h) ^ e) * 8;

  const v4f vzero = {0.f, 0.f, 0.f, 0.f};
  v4f acc[4][4];
#pragma unroll
  for (int mt = 0; mt < 4; ++mt)
#pragma unroll
    for (int nt = 0; nt < 4; ++nt) acc[mt][nt] = vzero;

  float4 a0[4], a1[4];   // f32 A-chunk for current it

#define STAGE_A(bufA, jj, s_)                                   \
  {                                                             \
    const float s = (s_);                                       \
    uint4 pk;                                                   \
    pk.x = cvtpk(a0[jj].x * s, a0[jj].y * s);                   \
    pk.y = cvtpk(a0[jj].z * s, a0[jj].w * s);                   \
    pk.z = cvtpk(a1[jj].x * s, a1[jj].y * s);                   \
    pk.w = cvtpk(a1[jj].z * s, a1[jj].w * s);                   \
    *(uint4*)(&As[bufA][aOffL[jj]]) = pk;                       \
  }
#define WSEL(jj, sdd) ((sdd) < 4 ? wA[jj][(sdd)] : wB[jj][(sdd)-4])

#define DS_READ(bufA, bufB, h)                                          \
  _Pragma("unroll") for (int mt = 0; mt < 4; ++mt)                      \
    af[mt] = *(const v8s*)(&As[bufA][(aRow + mt * 16) * BK + aC[h]]);   \
  _Pragma("unroll") for (int nt = 0; nt < 4; ++nt)                      \
    bf[nt] = *(const v8s*)(&Bs[bufB][(bRow + nt * 16) * BK + aC[h]]);

#define MFMA16()                                                        \
  __builtin_amdgcn_s_barrier();                                         \
  asm volatile("s_waitcnt lgkmcnt(0)" ::: "memory");                    \
  __builtin_amdgcn_sched_barrier(0);                                    \
  __builtin_amdgcn_s_setprio(1);                                        \
  _Pragma("unroll") for (int mt = 0; mt < 4; ++mt)                      \
    _Pragma("unroll") for (int nt = 0; nt < 4; ++nt)                    \
      acc[mt][nt] = __builtin_amdgcn_mfma_f32_16x16x32_bf16(            \
          af[mt], bf[nt], acc[mt][nt], 0, 0, 0);                        \
  __builtin_amdgcn_s_setprio(0);

  // ---- prologue: A(it0) regs; B(t=0)->Bs[0]; B(t=1 = dd1)->Bs[1]; A'(0)
#pragma unroll
  for (int j = 0; j < 4; ++j) {
    const float4* ap = (const float4*)aBase[j];
    a0[j] = ap[0]; a1[j] = ap[1];
  }
#pragma unroll
  for (int j = 0; j < 2; ++j) gload_lds16(bBase[j], &Bs[0][bOffL[j]]);
#pragma unroll
  for (int j = 0; j < 2; ++j)
    gload_lds16(bBase[j] + (size_t)(OUT_ * IN_), &Bs[1][bOffL[j]]);
#pragma unroll
  for (int j = 0; j < 4; ++j) STAGE_A(0, j, wA[j].x);        // dd=0 scale
  asm volatile("s_waitcnt vmcnt(2) lgkmcnt(0)" ::: "memory"); // B(0) done
  __builtin_amdgcn_s_barrier();

  // ---- main: t = it*8 + dd; tile t uses As[dd&1], Bs[dd&3]
  for (int it = 0; it < IN_ / BK; ++it) {
#pragma unroll
    for (int dd = 0; dd < D_; ++dd) {
      const int cA = dd & 1, nA = cA ^ 1;
      const int cB = dd & 3, sB = (dd + 2) & 3;
      const int sdd1 = (dd + 1) & 7;            // A'-staging target dd
      const int sdd2 = (dd + 2) & 7;            // B-staging target dd
      const bool lastTile  = (it == 15) && (dd == 7);
      const bool skipBload = (it == 15) && (dd >= 6);
      const int  sit2 = (dd >= 6) ? it + 1 : it;

      // ================= phase 0 (h=0) =================
      {
        v8s af[4], bf[4];
        DS_READ(cA, cB, 0);
        if (dd == 6) {          // write A'(dd7) fully from OLD regs
#pragma unroll
          for (int j = 0; j < 4; ++j) STAGE_A(nA, j, WSEL(j, 7));
        } else if (!lastTile) {
#pragma unroll
          for (int j = 0; j < 2; ++j) STAGE_A(nA, j, WSEL(j, sdd1));
        }
        if (!skipBload)
          gload_lds16(bBase[0] + (size_t)sdd2 * (OUT_ * IN_) + sit2 * BK,
                      &Bs[sB][bOffL[0]]);
        MFMA16();
        __builtin_amdgcn_s_barrier();
      }

      // ================= phase 1 (h=1) =================
      {
        v8s af[4], bf[4];
        DS_READ(cA, cB, 1);
        if (dd == 6) {
          if (it < 15) {                        // A f32 reload for it+1
#pragma unroll
            for (int j = 0; j < 4; ++j) {
              const float4* ap = (const float4*)(aBase[j] + (it + 1) * BK);
              a0[j] = ap[0]; a1[j] = ap[1];
            }
          }
        } else if (!lastTile) {
#pragma unroll
          for (int j = 2; j < 4; ++j) STAGE_A(nA, j, WSEL(j, sdd1));
        }
        if (!skipBload)
          gload_lds16(bBase[1] + (size_t)sdd2 * (OUT_ * IN_) + sit2 * BK,
                      &Bs[sB][bOffL[1]]);
        MFMA16();
        if (!lastTile) {
          if (dd == 6) {
            if (it < 15)
              asm volatile("s_waitcnt vmcnt(10)" ::: "memory");
            else
              asm volatile("s_waitcnt vmcnt(0)" ::: "memory");
          } else {
            asm volatile("s_waitcnt vmcnt(2)" ::: "memory");
          }
          __builtin_amdgcn_s_barrier();
        }
      }
    }
  }

  // ---- epilogue: add bias term sum_d w[b,d]*biases[d,o], plain stores
  float bcol[4][8];
#pragma unroll
  for (int nt = 0; nt < 4; ++nt) {
    const int col = n0 + wc * 64 + nt * 16 + l16;
#pragma unroll
    for (int dd = 0; dd < 8; ++dd) bcol[nt][dd] = biases[dd * OUT_ + col];
  }
#pragma unroll
  for (int mt = 0; mt < 4; ++mt) {
#pragma unroll
    for (int r = 0; r < 4; ++r) {
      const int grow = m0 + wr * 64 + mt * 16 + quad * 4 + r;
      const v4f* wp = (const v4f*)(w + (size_t)grow * D_);
      const v4f wa = wp[0], wb = wp[1];
#pragma unroll
      for (int nt = 0; nt < 4; ++nt) {
        const int col = n0 + wc * 64 + nt * 16 + l16;
        const float bias = wa[0] * bcol[nt][0] + wa[1] * bcol[nt][1] +
                           wa[2] * bcol[nt][2] + wa[3] * bcol[nt][3] +
                           wb[0] * bcol[nt][4] + wb[1] * bcol[nt][5] +
                           wb[2] * bcol[nt][6] + wb[3] * bcol[nt][7];
        out[(size_t)grow * OUT_ + col] = acc[mt][nt][r] + bias;
      }
    }
  }
}

extern "C" void kernel_launch(void* const* d_in, const int* in_sizes, int n_in,
                              void* d_out, int out_size, void* d_ws, size_t ws_size,
                              hipStream_t stream) {
  const float* input   = (const float*)d_in[0];
  const float* w       = (const float*)d_in[1];
  const float* weights = (const float*)d_in[2];
  const float* biases  = (const float*)d_in[3];
  float* out = (float*)d_out;

  u16* wtBf = (u16*)d_ws;                               // 16 MB

  const int nF4 = (D_ * OUT_ * IN_) / 4;                // one float4 / thread
  convert_w<<<dim3(nF4 / 256), 256, 0, stream>>>(weights, wtBf);
  gemm_8p<<<dim3(256), 512, 0, stream>>>(input, wtBf, w, biases, out);
}

// Round 6
// 236.072 us; speedup vs baseline: 1.1838x; 1.1838x over previous
//
#include <hip/hip_runtime.h>
#include <stdint.h>

typedef unsigned short u16;
typedef float v4f __attribute__((ext_vector_type(4)));
typedef short v8s __attribute__((ext_vector_type(8)));

#define B_   8192
#define IN_  1024
#define OUT_ 1024
#define D_   8

#define BM 128
#define BN 128
#define BK 64             // K-tile per phase: 32 MFMAs, 1 barrier

__device__ __forceinline__ u16 f2bf(float f) {
  uint32_t u = __float_as_uint(f);
  u += 0x7fffu + ((u >> 16) & 1u);   // RTNE (inputs finite)
  return (u16)(u >> 16);
}

// ---- prep: input + weights f32 -> bf16 (R2-proven convert_both) ------------
__global__ __launch_bounds__(256) void convert_both(
    const float* __restrict__ input, const float* __restrict__ weights,
    u16* __restrict__ inBf, u16* __restrict__ wtBf) {
  int i4 = blockIdx.x * blockDim.x + threadIdx.x;
  const int n4 = (B_ * IN_) / 4;
  const float* src;
  u16* dst;
  int idx;
  if (i4 < n4) { src = input;   dst = inBf; idx = i4; }
  else         { src = weights; dst = wtBf; idx = i4 - n4; }
  float4 v = ((const float4*)src)[idx];
  ushort4 o;
  o.x = f2bf(v.x); o.y = f2bf(v.y); o.z = f2bf(v.z); o.w = f2bf(v.w);
  ((ushort4*)dst)[idx] = o;
}

__device__ __forceinline__ void gload_lds16(const u16* g, u16* l) {
  typedef __attribute__((address_space(1))) void gvoid;
  typedef __attribute__((address_space(3))) void lvoid;
  __builtin_amdgcn_global_load_lds((gvoid*)g, (lvoid*)l, 16, 0, 0);
}

// ---- GEMM with telescoping accumulator rescale -----------------------------
// out[b,o] = sum_d w[b,d] * (input[b,:] . weights[d,o,:]) + bias-term.
// Instead of scaling A (R2-R4: f32 load + cvt VALU + ds_write per tile) or a
// second accumulator bank (R1: occupancy kill), keep ONE acc with invariant
// "acc is in units of 1/g(w[row,dd_cur])":
//   at plane boundary: acc *= g(w[row,prev]) / g(w[row,next])   (7 interludes)
//   epilogue:          out  = acc * g(w[row,7]) + bias
// Telescoping makes each plane's effective weight exactly g(w[d]);
// g(x)=max(x,1e-30) guards w==0 (contribution underflows to 0, correct).
// Errors inserted at inflated scale deflate with the same ratios -> numerics
// comparable to the bf16-rounded baseline.
// The K-loop is therefore pure gload_lds staging (A 4 + B 4 per tile, no
// ds_write / cvt / f32 loads) + R4's counted-vmcnt single-barrier schedule.
// vmcnt ledger (4 loads per issue-group, FIFO):
//   top of t: issue A(t+1) then B(t+2); queue [B(t+1), A(t+1), B(t+2)]
//   end of t: need B(t+1)+A(t+1) -> vmcnt(4).  t==126: vmcnt(0).  t==127: none.
__global__ __launch_bounds__(256, 2) void gemm_rs(
    const u16* __restrict__ A,        // [B_][IN_] bf16 input (unscaled)
    const u16* __restrict__ Wt,       // [D_][OUT_][IN_] bf16
    const float* __restrict__ w,      // [B_][D_]
    const float* __restrict__ biases, // [D_][OUT_]
    float* __restrict__ out) {        // [B_][OUT_]
  __shared__ __align__(16) u16 As[2][BM * BK];   // 32 KB
  __shared__ __align__(16) u16 Bs[3][BN * BK];   // 48 KB -> 80 KB: 2 blk/CU

  // R0-proven mapping: all 8 blocks sharing an A-panel are co-XCD.
  const int id   = blockIdx.x;                // 512 blocks
  const int xcd  = id & 7;
  const int slot = id >> 3;
  const int by   = xcd + ((slot & 7) << 3);   // 0..63
  const int bx   = slot >> 3;                 // 0..7

  const int tid  = threadIdx.x;
  const int wid  = tid >> 6;
  const int lane = tid & 63;
  const int wr   = wid >> 1, wc = wid & 1;
  const int quad = lane >> 4, l16 = lane & 15;
  const int m0   = by * BM;
  const int n0   = bx * BN;

  // staging geometry (proven): chunk c = wid*256+j*64+lane; row = c>>3;
  // LDS chunk (lane&7) holds global chunk swz = (lane&7)^((lane>>3)&7).
  const int swz  = (lane & 7) ^ ((lane >> 3) & 7);
  const int rowS = wid * 32 + (lane >> 3);    // + j*8
  const u16* aBase[4];
  const u16* bBase[4];
  int cOff[4];
#pragma unroll
  for (int j = 0; j < 4; ++j) {
    const int row = rowS + j * 8;
    aBase[j] = A  + (size_t)(m0 + row) * IN_ + swz * 8;
    bBase[j] = Wt + (size_t)(n0 + row) * IN_ + swz * 8;
    cOff[j]  = (wid * 256 + j * 64 + lane) * 8;
  }

  // fragment LDS offsets (u16 index), de-swizzled
  const int aRow = wr * 64 + l16;
  const int bRow = wc * 64 + l16;
  const int e    = l16 & 7;
  int aCol[2];
#pragma unroll
  for (int h = 0; h < 2; ++h) aCol[h] = ((quad + 4 * h) ^ e) * 8;

  const v4f vzero = {0.f, 0.f, 0.f, 0.f};
  v4f acc[4][4];
#pragma unroll
  for (int mt = 0; mt < 4; ++mt)
#pragma unroll
    for (int nt = 0; nt < 4; ++nt) acc[mt][nt] = vzero;

  // wp[mt][r] = g(w[row, current plane]); init plane 0
  float wp[4][4];
#pragma unroll
  for (int mt = 0; mt < 4; ++mt)
#pragma unroll
    for (int r = 0; r < 4; ++r) {
      const int grow = m0 + wr * 64 + mt * 16 + quad * 4 + r;
      wp[mt][r] = fmaxf(w[(size_t)grow * D_], 1e-30f);
    }

  // rotating buffers
  u16* aC_ = As[0];
  u16* aN  = As[1];
  u16* bC  = Bs[0];
  u16* bN  = Bs[1];
  u16* bS  = Bs[2];

  // ---- prologue: A(slice 0) -> aC_, B(t=0) -> bC, B(t=1) -> bN
#pragma unroll
  for (int j = 0; j < 4; ++j) gload_lds16(aBase[j], aC_ + cOff[j]);
#pragma unroll
  for (int j = 0; j < 4; ++j) gload_lds16(bBase[j], bC + cOff[j]);
#pragma unroll
  for (int j = 0; j < 4; ++j)
    gload_lds16(bBase[j] + (size_t)BK, bN + cOff[j]);   // (dd0, it1)
  asm volatile("s_waitcnt vmcnt(4) lgkmcnt(0)" ::: "memory"); // A0+B0 done
  __builtin_amdgcn_s_barrier();

  // ---- main: dd outer (7 cheap rescale interludes), it inner, t = dd*16+it
  for (int dd = 0; dd < D_; ++dd) {
    if (dd > 0) {
      // plane transition: acc *= g(w[:,dd-1]) / g(w[:,dd])
#pragma unroll
      for (int mt = 0; mt < 4; ++mt) {
#pragma unroll
        for (int r = 0; r < 4; ++r) {
          const int grow = m0 + wr * 64 + mt * 16 + quad * 4 + r;
          const float wn = fmaxf(w[(size_t)grow * D_ + dd], 1e-30f);
          const float ratio = wp[mt][r] / wn;
          wp[mt][r] = wn;
#pragma unroll
          for (int nt = 0; nt < 4; ++nt) acc[mt][nt][r] *= ratio;
        }
      }
    }
    for (int it = 0; it < 16; ++it) {
      const int t = dd * 16 + it;

      // -- stage A slice (t+1), 1-ahead (A independent of dd; slice wraps)
      if (t < 127) {
        const int sit = (it + 1) & 15;
#pragma unroll
        for (int j = 0; j < 4; ++j)
          gload_lds16(aBase[j] + sit * BK, aN + cOff[j]);
      }
      // -- stage B tile (t+2), 2-ahead (issued AFTER A: keeps A older in FIFO)
      if (t < 126) {
        const int it2  = it + 2;
        const int sdd2 = dd + (it2 >> 4);
        const int sit2 = it2 & 15;
#pragma unroll
        for (int j = 0; j < 4; ++j)
          gload_lds16(bBase[j] + (size_t)sdd2 * (OUT_ * IN_) + sit2 * BK,
                      bS + cOff[j]);
      }

      // -- compute on aC_, bC
      __builtin_amdgcn_s_setprio(1);
#pragma unroll
      for (int h = 0; h < 2; ++h) {
        v8s af[4], bf[4];
#pragma unroll
        for (int mt = 0; mt < 4; ++mt)
          af[mt] = *(const v8s*)(aC_ + (aRow + mt * 16) * BK + aCol[h]);
#pragma unroll
        for (int nt = 0; nt < 4; ++nt)
          bf[nt] = *(const v8s*)(bC + (bRow + nt * 16) * BK + aCol[h]);
#pragma unroll
        for (int mt = 0; mt < 4; ++mt)
#pragma unroll
          for (int nt = 0; nt < 4; ++nt)
            acc[mt][nt] = __builtin_amdgcn_mfma_f32_16x16x32_bf16(
                af[mt], bf[nt], acc[mt][nt], 0, 0, 0);
      }
      __builtin_amdgcn_s_setprio(0);

      // -- counted wait + barrier
      if (t < 126) {
        asm volatile("s_waitcnt vmcnt(4)" ::: "memory");  // B(t+1)+A(t+1) done
        __builtin_amdgcn_s_barrier();
      } else if (t == 126) {
        asm volatile("s_waitcnt vmcnt(0)" ::: "memory");  // drain for last tile
        __builtin_amdgcn_s_barrier();
      }

      // -- rotate buffers
      u16* ta = aC_; aC_ = aN; aN = ta;
      u16* tb = bC; bC = bN; bN = bS; bS = tb;
    }
  }

  // ---- epilogue: out = acc * g(w[:,7]) + sum_d w[b,d]*biases[d,o]
  float bcol[4][8];
#pragma unroll
  for (int nt = 0; nt < 4; ++nt) {
    const int col = n0 + wc * 64 + nt * 16 + l16;
#pragma unroll
    for (int dd = 0; dd < 8; ++dd) bcol[nt][dd] = biases[dd * OUT_ + col];
  }
#pragma unroll
  for (int mt = 0; mt < 4; ++mt) {
#pragma unroll
    for (int r = 0; r < 4; ++r) {
      const int grow = m0 + wr * 64 + mt * 16 + quad * 4 + r;
      const v4f* wpg = (const v4f*)(w + (size_t)grow * D_);
      const v4f wa = wpg[0], wb = wpg[1];
      const float wlast = wp[mt][r];
#pragma unroll
      for (int nt = 0; nt < 4; ++nt) {
        const int col = n0 + wc * 64 + nt * 16 + l16;
        const float bias = wa[0] * bcol[nt][0] + wa[1] * bcol[nt][1] +
                           wa[2] * bcol[nt][2] + wa[3] * bcol[nt][3] +
                           wb[0] * bcol[nt][4] + wb[1] * bcol[nt][5] +
                           wb[2] * bcol[nt][6] + wb[3] * bcol[nt][7];
        out[(size_t)grow * OUT_ + col] = acc[mt][nt][r] * wlast + bias;
      }
    }
  }
}

extern "C" void kernel_launch(void* const* d_in, const int* in_sizes, int n_in,
                              void* d_out, int out_size, void* d_ws, size_t ws_size,
                              hipStream_t stream) {
  const float* input   = (const float*)d_in[0];
  const float* w       = (const float*)d_in[1];
  const float* weights = (const float*)d_in[2];
  const float* biases  = (const float*)d_in[3];
  float* out = (float*)d_out;

  u16* inBf = (u16*)d_ws;                               // 16 MB
  u16* wtBf = inBf + (size_t)B_ * IN_;                  // 16 MB

  const int totalF4 = (B_ * IN_ + D_ * OUT_ * IN_) / 4;
  convert_both<<<dim3(totalF4 / 256), 256, 0, stream>>>(input, weights, inBf, wtBf);
  gemm_rs<<<dim3(512), 256, 0, stream>>>(inBf, wtBf, w, biases, out);
}